// Round 1
// baseline (361.196 us; speedup 1.0000x reference)
//
#include <hip/hip_runtime.h>

#define IN_H 512
#define IN_W 512
#define OUT_H 224
#define OUT_W 224

// antialiased bilinear resize, 512->224 both dims.
// inv_scale = 512/224, kernel_scale = inv_scale (antialias downsample),
// weight(i) = max(0, 1 - |c - i| * 224/512), normalized per output index.
// Max 5 taps per dim.

__global__ __launch_bounds__(256) void resize_aa_kernel(
    const float* __restrict__ in, float* __restrict__ out, int total) {
    int idx = blockIdx.x * blockDim.x + threadIdx.x;
    if (idx >= total) return;

    int x  = idx % OUT_W;
    int t  = idx / OUT_W;
    int y  = t % OUT_H;
    int bc = t / OUT_H;

    const float inv_scale = (float)IN_W / (float)OUT_W;  // 2.285714
    const float ks        = inv_scale;                    // kernel scale
    const float scl       = (float)OUT_W / (float)IN_W;   // 0.4375

    // ---- x weights (5 taps) ----
    float cx = (x + 0.5f) * inv_scale - 0.5f;
    int ix0 = (int)ceilf(cx - ks);
    float wx[5];
    int   ix[5];
    float sx = 0.f;
#pragma unroll
    for (int j = 0; j < 5; ++j) {
        int i = ix0 + j;
        float w = 1.f - fabsf(cx - (float)i) * scl;
        w = fmaxf(w, 0.f);
        if (i < 0 || i >= IN_W) w = 0.f;
        wx[j] = w;
        sx += w;
        ix[j] = min(max(i, 0), IN_W - 1);
    }

    // ---- y weights (5 taps) ----
    float cy = (y + 0.5f) * inv_scale - 0.5f;
    int iy0 = (int)ceilf(cy - ks);
    float wy[5];
    int   iy[5];
    float sy = 0.f;
#pragma unroll
    for (int j = 0; j < 5; ++j) {
        int i = iy0 + j;
        float w = 1.f - fabsf(cy - (float)i) * scl;
        w = fmaxf(w, 0.f);
        if (i < 0 || i >= IN_H) w = 0.f;
        wy[j] = w;
        sy += w;
        iy[j] = min(max(i, 0), IN_H - 1);
    }

    float norm = 1.f / (sx * sy);

    const float* base = in + (size_t)bc * (IN_H * IN_W);
    float acc = 0.f;
#pragma unroll
    for (int jy = 0; jy < 5; ++jy) {
        const float* rp = base + (size_t)iy[jy] * IN_W;
        float racc = 0.f;
#pragma unroll
        for (int jx = 0; jx < 5; ++jx) {
            racc = fmaf(wx[jx], rp[ix[jx]], racc);
        }
        acc = fmaf(wy[jy], racc, acc);
    }

    out[idx] = acc * norm;
}

extern "C" void kernel_launch(void* const* d_in, const int* in_sizes, int n_in,
                              void* d_out, int out_size, void* d_ws, size_t ws_size,
                              hipStream_t stream) {
    const float* in = (const float*)d_in[0];
    float* out = (float*)d_out;
    int total = out_size;  // 64*3*224*224 = 9,633,792
    dim3 block(256);
    dim3 grid((total + 255) / 256);
    hipLaunchKernelGGL(resize_aa_kernel, grid, block, 0, stream, in, out, total);
}

// Round 2
// 342.008 us; speedup vs baseline: 1.0561x; 1.0561x over previous
//
#include <hip/hip_runtime.h>

#define IN_H 512
#define IN_W 512
#define OUT_H 224
#define OUT_W 224
#define OY 8            // output rows per block
#define NROWS 21        // input rows needed: 8*16/7 span = 16, +5 taps
#define BLOCK 256

// Antialiased bilinear 512->224 (scale 7/16 per dim), separable triangle
// kernel, per-dim normalized weights, max 5 taps. Fused one-kernel version:
// stage 21 input rows -> horizontal resize in LDS -> vertical resize -> store.

__global__ __launch_bounds__(BLOCK) void resize_aa_fused(
    const float* __restrict__ in, float* __restrict__ out) {

    __shared__ float s_in[NROWS][IN_W];     // 43008 B
    __shared__ float s_h[NROWS][OUT_W];     // 18816 B
    __shared__ float s_wx[OUT_W][5];        // 4480 B (pre-normalized)
    __shared__ int   s_ix0[OUT_W];          // 896 B
    __shared__ float s_wy[OY][5];           // 160 B (pre-normalized)
    __shared__ int   s_ro[OY];              // 32 B

    const int bc  = blockIdx.x;             // 0..191  (B*C)
    const int oy0 = blockIdx.y * OY;        // 0..216
    const int tid = threadIdx.x;

    const float inv_scale = 16.f / 7.f;     // in/out
    const float scl       = 7.f / 16.f;     // out/in

    // first input row needed by this block (may be <0; loads are clamped,
    // weights for OOB taps are zero)
    const int iy_first = (int)ceilf((oy0 + 0.5f) * inv_scale - 0.5f - inv_scale);

    // ---- per-ox horizontal weight LUT (pre-normalized) ----
    if (tid < OUT_W) {
        float cx  = (tid + 0.5f) * inv_scale - 0.5f;
        int   ix0 = (int)ceilf(cx - inv_scale);
        float w[5];
        float s = 0.f;
#pragma unroll
        for (int j = 0; j < 5; ++j) {
            int i = ix0 + j;
            float ww = 1.f - fabsf(cx - (float)i) * scl;
            ww = fmaxf(ww, 0.f);
            if (i < 0 || i >= IN_W) ww = 0.f;
            w[j] = ww;
            s += ww;
        }
        float invs = 1.f / s;
#pragma unroll
        for (int j = 0; j < 5; ++j) s_wx[tid][j] = w[j] * invs;
        s_ix0[tid] = ix0;
    }

    // ---- per-oy vertical weight LUT (pre-normalized) ----
    if (tid < OY) {
        int   oy  = oy0 + tid;
        float cy  = (oy + 0.5f) * inv_scale - 0.5f;
        int   iy0 = (int)ceilf(cy - inv_scale);
        float w[5];
        float s = 0.f;
#pragma unroll
        for (int j = 0; j < 5; ++j) {
            int i = iy0 + j;
            float ww = 1.f - fabsf(cy - (float)i) * scl;
            ww = fmaxf(ww, 0.f);
            if (i < 0 || i >= IN_H) ww = 0.f;
            w[j] = ww;
            s += ww;
        }
        float invs = 1.f / s;
#pragma unroll
        for (int j = 0; j < 5; ++j) s_wy[tid][j] = w[j] * invs;
        s_ro[tid] = iy0 - iy_first;   // 0..16, taps stay < NROWS
    }

    // ---- stage 21 rows, coalesced float4 ----
    const float* src = in + (size_t)bc * (IN_H * IN_W);
    for (int idx = tid; idx < NROWS * (IN_W / 4); idx += BLOCK) {
        int r  = idx >> 7;          // /128
        int c4 = idx & 127;
        int row = min(max(iy_first + r, 0), IN_H - 1);
        float4 v = ((const float4*)(src + (size_t)row * IN_W))[c4];
        ((float4*)(&s_in[r][0]))[c4] = v;
    }

    __syncthreads();

    // ---- horizontal pass: s_in[21][512] -> s_h[21][224] ----
    for (int idx = tid; idx < NROWS * OUT_W; idx += BLOCK) {
        int r  = idx / OUT_W;
        int ox = idx - r * OUT_W;
        int ix0 = s_ix0[ox];
        float acc = 0.f;
#pragma unroll
        for (int j = 0; j < 5; ++j) {
            int i = min(max(ix0 + j, 0), IN_W - 1);   // OOB taps have w=0
            acc = fmaf(s_wx[ox][j], s_in[r][i], acc);
        }
        s_h[r][ox] = acc;
    }

    __syncthreads();

    // ---- vertical pass: s_h -> out, stride-1 LDS reads, coalesced store ----
    for (int idx = tid; idx < OY * OUT_W; idx += BLOCK) {
        int t  = idx / OUT_W;
        int ox = idx - t * OUT_W;
        int ro = s_ro[t];
        float acc = 0.f;
#pragma unroll
        for (int j = 0; j < 5; ++j) {
            acc = fmaf(s_wy[t][j], s_h[ro + j][ox], acc);
        }
        out[((size_t)bc * OUT_H + (oy0 + t)) * OUT_W + ox] = acc;
    }
}

extern "C" void kernel_launch(void* const* d_in, const int* in_sizes, int n_in,
                              void* d_out, int out_size, void* d_ws, size_t ws_size,
                              hipStream_t stream) {
    const float* in = (const float*)d_in[0];
    float* out = (float*)d_out;
    dim3 block(BLOCK);
    dim3 grid(64 * 3, OUT_H / OY);   // (192, 28)
    hipLaunchKernelGGL(resize_aa_fused, grid, block, 0, stream, in, out);
}

// Round 3
// 282.803 us; speedup vs baseline: 1.2772x; 1.2094x over previous
//
#include <hip/hip_runtime.h>

#define IN_H 512
#define IN_W 512
#define OUT_H 224
#define OUT_W 224
#define OY 4            // output rows per block
#define BLOCK 256

// Antialiased bilinear 512->224 (scale 7/16), separable triangle kernel,
// per-dim normalized weights, max 5 taps/dim.
// Vertical-first fused: vertical reduction straight from global (coalesced
// float4, taps at row stride) into small LDS, then horizontal gather from LDS.
// LDS ~13.4 KB -> 8 blocks/CU (occupancy-friendly), 1 barrier.

__global__ __launch_bounds__(BLOCK) void resize_aa_vfirst(
    const float* __restrict__ in, float* __restrict__ out) {

    __shared__ float s_v[OY][IN_W];     // 8192 B  (vertically resized rows)
    __shared__ float s_wx[OUT_W][5];    // 4480 B  (pre-normalized x weights)
    __shared__ int   s_ix0[OUT_W];      // 896 B

    const int bc  = blockIdx.x;          // 0..191
    const int oy0 = blockIdx.y * OY;     // 0..220
    const int tid = threadIdx.x;

    const float inv_scale = 16.f / 7.f;  // in/out = 2.285714
    const float scl       = 7.f / 16.f;  // out/in

    // ---- horizontal weight LUT (pre-normalized), once per block ----
    if (tid < OUT_W) {
        float cx  = (tid + 0.5f) * inv_scale - 0.5f;
        int   ix0 = (int)ceilf(cx - inv_scale);
        float w[5];
        float s = 0.f;
#pragma unroll
        for (int j = 0; j < 5; ++j) {
            int i = ix0 + j;
            float ww = 1.f - fabsf(cx - (float)i) * scl;
            ww = fmaxf(ww, 0.f);
            if (i < 0 || i >= IN_W) ww = 0.f;
            w[j] = ww;
            s += ww;
        }
        float invs = 1.f / s;
#pragma unroll
        for (int j = 0; j < 5; ++j) s_wx[tid][j] = w[j] * invs;
        s_ix0[tid] = ix0;
    }

    // ---- vertical pass: global (coalesced float4) -> s_v ----
    // quads: OY rows x 128 float4 columns = 512 quads, 2 per thread
    const float* src = in + (size_t)bc * (IN_H * IN_W);
    for (int q = tid; q < OY * (IN_W / 4); q += BLOCK) {
        int t  = q >> 7;                 // quad row (0..OY-1)
        int x0 = (q & 127) << 2;         // column of this float4
        float cy  = (oy0 + t + 0.5f) * inv_scale - 0.5f;
        int   iy0 = (int)ceilf(cy - inv_scale);
        float4 acc = make_float4(0.f, 0.f, 0.f, 0.f);
        float s = 0.f;
#pragma unroll
        for (int j = 0; j < 5; ++j) {
            int i = iy0 + j;
            float ww = 1.f - fabsf(cy - (float)i) * scl;
            ww = fmaxf(ww, 0.f);
            if (i < 0 || i >= IN_H) ww = 0.f;
            s += ww;
            int r = min(max(i, 0), IN_H - 1);
            float4 v = *(const float4*)(src + (size_t)r * IN_W + x0);
            acc.x = fmaf(ww, v.x, acc.x);
            acc.y = fmaf(ww, v.y, acc.y);
            acc.z = fmaf(ww, v.z, acc.z);
            acc.w = fmaf(ww, v.w, acc.w);
        }
        float invs = 1.f / s;
        acc.x *= invs; acc.y *= invs; acc.z *= invs; acc.w *= invs;
        *(float4*)(&s_v[t][x0]) = acc;
    }

    __syncthreads();

    // ---- horizontal pass: s_v -> out (coalesced store) ----
    for (int idx = tid; idx < OY * OUT_W; idx += BLOCK) {
        int t  = idx / OUT_W;
        int ox = idx - t * OUT_W;
        int ix0 = s_ix0[ox];
        float acc = 0.f;
#pragma unroll
        for (int j = 0; j < 5; ++j) {
            int c = min(max(ix0 + j, 0), IN_W - 1);  // OOB taps have w=0
            acc = fmaf(s_wx[ox][j], s_v[t][c], acc);
        }
        out[((size_t)bc * OUT_H + (oy0 + t)) * OUT_W + ox] = acc;
    }
}

extern "C" void kernel_launch(void* const* d_in, const int* in_sizes, int n_in,
                              void* d_out, int out_size, void* d_ws, size_t ws_size,
                              hipStream_t stream) {
    const float* in = (const float*)d_in[0];
    float* out = (float*)d_out;
    dim3 block(BLOCK);
    dim3 grid(64 * 3, OUT_H / OY);   // (192, 56)
    hipLaunchKernelGGL(resize_aa_vfirst, grid, block, 0, stream, in, out);
}